// Round 11
// baseline (238.253 us; speedup 1.0000x reference)
//
#include <hip/hip_runtime.h>
#include <hip/hip_bf16.h>

#define NB 4
#define SEQ 1024
#define DM 1024
#define NH 16
#define HD 64
#define QSCALE 0.125f
#define NTOK (NB*SEQ)

using f32x4  = __attribute__((ext_vector_type(4))) float;
using bf16x8 = __attribute__((ext_vector_type(8))) short;
using s16x4  = __attribute__((ext_vector_type(4))) short;

__device__ __forceinline__ short f2bf(float x){
  __hip_bfloat16 h = __float2bfloat16(x);
  return *reinterpret_cast<short*>(&h);
}
__device__ __forceinline__ float bf2f(short x){
  __hip_bfloat16 h; *reinterpret_cast<short*>(&h) = x;
  return __bfloat162float(h);
}
// fp8 e4m3 (OCP on gfx950) encode/decode via the HW cvt pair — roundtrip-consistent.
__device__ __forceinline__ unsigned char f2fp8(float x){
  int d = __builtin_amdgcn_cvt_pk_fp8_f32(x, x, 0, false);
  return (unsigned char)(d & 0xff);
}
__device__ __forceinline__ float fp82f(unsigned char x){
  return __builtin_amdgcn_cvt_f32_fp8((int)x, 0);
}

// async global->LDS, 16B per lane; LDS dest = wave-uniform base + lane*16.
__device__ __forceinline__ void gld16(const void* g, void* l){
  __builtin_amdgcn_global_load_lds(
      (const __attribute__((address_space(1))) unsigned int*)g,
      (__attribute__((address_space(3))) unsigned int*)l, 16, 0, 0);
}

// ---------------- fp32 -> bf16 convert, all 7 tensors in one dispatch ----------
__global__ void cvt_all(const float* __restrict__ a0, const float* __restrict__ a1,
                        const float* __restrict__ a2, const float* __restrict__ a3,
                        const float* __restrict__ a4, const float* __restrict__ a5,
                        const float* __restrict__ a6,
                        short* o0, short* o1, short* o2, short* o3,
                        short* o4, short* o5, short* o6, int big4, int small4){
  int i = blockIdx.x * blockDim.x + threadIdx.x;
  int y = blockIdx.y;
  int n4 = (y < 3) ? big4 : small4;
  if (i >= n4) return;
  const float* in; short* out;
  if      (y == 0){ in = a0; out = o0; }
  else if (y == 1){ in = a1; out = o1; }
  else if (y == 2){ in = a2; out = o2; }
  else if (y == 3){ in = a3; out = o3; }
  else if (y == 4){ in = a4; out = o4; }
  else if (y == 5){ in = a5; out = o5; }
  else            { in = a6; out = o6; }
  float4 v = reinterpret_cast<const float4*>(in)[i];
  s16x4 o;
  o[0] = f2bf(v.x); o[1] = f2bf(v.y); o[2] = f2bf(v.z); o[3] = f2bf(v.w);
  reinterpret_cast<s16x4*>(out)[i] = o;
}

// ------------- fused Q/K/V projection GEMMs, m97 structure (R6-proven) ----------
__global__ __launch_bounds__(256) void proj_gemm(
    const short* __restrict__ qb, const short* __restrict__ kb, const short* __restrict__ vb,
    const short* __restrict__ wqb, const short* __restrict__ wkb, const short* __restrict__ wvb,
    const float* __restrict__ bq, const float* __restrict__ bk, const float* __restrict__ bv,
    short* __restrict__ qhb, short* __restrict__ khb, short* __restrict__ vTb)
{
  __shared__ short As[128*32];
  __shared__ short Bs[128*32];
  const int t = threadIdx.x, w = t >> 6, l = t & 63, lr = l & 15, lg = l >> 4;
  const int wr = w >> 1, wc = w & 1;
  const int which = blockIdx.y >> 3;
  const short *A, *Bt;
  int m0, n0;
  if (which == 2){ A = wvb; Bt = vb; m0 = (blockIdx.y & 7)*128; n0 = blockIdx.x*128; }
  else if (which == 1){ A = kb; Bt = wkb; m0 = blockIdx.x*128; n0 = (blockIdx.y & 7)*128; }
  else { A = qb; Bt = wqb; m0 = blockIdx.x*128; n0 = (blockIdx.y & 7)*128; }
  f32x4 acc[4][4] = {};
  for (int k0 = 0; k0 < DM; k0 += 32){
    __syncthreads();
    #pragma unroll
    for (int i = 0; i < 2; ++i){
      int c = i*256 + t, row = c >> 2, sl = c & 3;
      gld16(A  + (size_t)(m0 + row)*DM + k0 + sl*8, &As[c*8]);
      gld16(Bt + (size_t)(n0 + row)*DM + k0 + sl*8, &Bs[c*8]);
    }
    __syncthreads();
    bf16x8 af[4], bfr[4];
    #pragma unroll
    for (int m = 0; m < 4; ++m)
      af[m] = *reinterpret_cast<const bf16x8*>(&As[(wr*64 + m*16 + lr)*32 + lg*8]);
    #pragma unroll
    for (int n = 0; n < 4; ++n)
      bfr[n] = *reinterpret_cast<const bf16x8*>(&Bs[(wc*64 + n*16 + lr)*32 + lg*8]);
    #pragma unroll
    for (int m = 0; m < 4; ++m)
      #pragma unroll
      for (int n = 0; n < 4; ++n)
        acc[m][n] = __builtin_amdgcn_mfma_f32_16x16x32_bf16(af[m], bfr[n], acc[m][n], 0, 0, 0);
  }
  #pragma unroll
  for (int m = 0; m < 4; ++m){
    int row = m0 + wr*64 + m*16 + lg*4;
    #pragma unroll
    for (int n = 0; n < 4; ++n){
      int col = n0 + wc*64 + n*16 + lr;
      #pragma unroll
      for (int e = 0; e < 4; ++e){
        if (which == 0)
          qhb[(size_t)(row + e)*DM + col] = f2bf((acc[m][n][e] + bq[col]) * QSCALE);
        else if (which == 1)
          khb[(size_t)(row + e)*DM + col] = f2bf(acc[m][n][e] + bk[col]);
        else
          vTb[(size_t)(row + e)*NTOK + col] = f2bf(acc[m][n][e] + bv[row + e]);
      }
    }
  }
}

// ------------- out GEMM: out = aob @ Wo^T + bo (R6-proven) ----------------------
__global__ __launch_bounds__(256) void out_gemm(const short* __restrict__ A,
    const short* __restrict__ Bt, const float* __restrict__ bias, float* __restrict__ out)
{
  __shared__ short As[128*32];
  __shared__ short Bs[128*32];
  const int t = threadIdx.x, w = t >> 6, l = t & 63, lr = l & 15, lg = l >> 4;
  const int wr = w >> 1, wc = w & 1;
  const int m0 = blockIdx.x*128, n0 = blockIdx.y*128;
  f32x4 acc[4][4] = {};
  for (int k0 = 0; k0 < DM; k0 += 32){
    __syncthreads();
    #pragma unroll
    for (int i = 0; i < 2; ++i){
      int c = i*256 + t, row = c >> 2, sl = c & 3;
      gld16(A  + (size_t)(m0 + row)*DM + k0 + sl*8, &As[c*8]);
      gld16(Bt + (size_t)(n0 + row)*DM + k0 + sl*8, &Bs[c*8]);
    }
    __syncthreads();
    bf16x8 af[4], bfr[4];
    #pragma unroll
    for (int m = 0; m < 4; ++m)
      af[m] = *reinterpret_cast<const bf16x8*>(&As[(wr*64 + m*16 + lr)*32 + lg*8]);
    #pragma unroll
    for (int n = 0; n < 4; ++n)
      bfr[n] = *reinterpret_cast<const bf16x8*>(&Bs[(wc*64 + n*16 + lr)*32 + lg*8]);
    #pragma unroll
    for (int m = 0; m < 4; ++m)
      #pragma unroll
      for (int n = 0; n < 4; ++n)
        acc[m][n] = __builtin_amdgcn_mfma_f32_16x16x32_bf16(af[m], bfr[n], acc[m][n], 0, 0, 0);
  }
  #pragma unroll
  for (int m = 0; m < 4; ++m){
    int row = m0 + wr*64 + m*16 + lg*4;
    #pragma unroll
    for (int n = 0; n < 4; ++n){
      int col = n0 + wc*64 + n*16 + lr;
      float bb = bias[col];
      #pragma unroll
      for (int e = 0; e < 4; ++e)
        out[(size_t)(row + e)*DM + col] = acc[m][n][e] + bb;
    }
  }
}

// ------------- rel scores (R6-proven): Rs[q][bh][k] fp8 -------------------------
__global__ __launch_bounds__(256) void relscore2(const short* __restrict__ qh,
    const float* __restrict__ rel, unsigned char* __restrict__ Rs)
{
  __shared__ short At[64*72];   // [bh][d]
  __shared__ short Bs[64*72];   // [k][d] bf16
  const int t = threadIdx.x, w = t >> 6, l = t & 63, lr = l & 15, lg = l >> 4;
  const int q = blockIdx.x;
  #pragma unroll
  for (int i = 0; i < 2; ++i){
    int c = t + i*256;
    int row = c >> 3, off = (c & 7) * 8;
    int b = row >> 4, h = row & 15;
    uint4 v = *reinterpret_cast<const uint4*>(qh + ((size_t)(b*SEQ + q)*NH + h)*HD + off);
    *reinterpret_cast<uint4*>(&At[row*72 + off]) = v;
  }
  __syncthreads();
  bf16x8 af[2];
  af[0] = *reinterpret_cast<const bf16x8*>(&At[(w*16 + lr)*72 + lg*8]);
  af[1] = *reinterpret_cast<const bf16x8*>(&At[(w*16 + lr)*72 + 32 + lg*8]);
  for (int k0 = 0; k0 < SEQ; k0 += 64){
    __syncthreads();
    #pragma unroll
    for (int i = 0; i < 4; ++i){
      int c = t + i*256;
      int row = c >> 4, off = (c & 15) * 4;
      float4 v = *reinterpret_cast<const float4*>(rel + ((size_t)q*SEQ + k0 + row)*HD + off);
      s16x4 o;
      o[0] = f2bf(v.x); o[1] = f2bf(v.y); o[2] = f2bf(v.z); o[3] = f2bf(v.w);
      *reinterpret_cast<s16x4*>(&Bs[row*72 + off]) = o;
    }
    __syncthreads();
    f32x4 acc[4] = {};
    #pragma unroll
    for (int s = 0; s < 2; ++s){
      #pragma unroll
      for (int tt = 0; tt < 4; ++tt){
        bf16x8 bf = *reinterpret_cast<const bf16x8*>(&Bs[(tt*16 + lr)*72 + s*32 + lg*8]);
        acc[tt] = __builtin_amdgcn_mfma_f32_16x16x32_bf16(af[s], bf, acc[tt], 0, 0, 0);
      }
    }
    #pragma unroll
    for (int tt = 0; tt < 4; ++tt){
      #pragma unroll
      for (int e = 0; e < 4; ++e){
        int bh = w*16 + lg*4 + e;
        Rs[((size_t)q*64 + bh)*SEQ + k0 + tt*16 + lr] = f2fp8(acc[tt][e]);
      }
    }
  }
}

// ------------- flash4b: R10 flash4, grid swapped to (q0, bh) for K/V L2 reuse ---
// Consecutive blocks now share one bh's K/V panels (256KB) -> L2-hot.
__global__ __launch_bounds__(256, 4) void flash4(const short* __restrict__ qh,
    const short* __restrict__ kh, const short* __restrict__ vT,
    const unsigned char* __restrict__ Rs, short* __restrict__ ao)
{
  __shared__ short KP[128*64];   // phase A: K [k][d] chunk^(row&7); phase B: P [q][k] swizzled
  __shared__ short Vt[64*128];   // [hd][k] chunk^(row&15) swizzle
  const int t = threadIdx.x, w = t >> 6, l = t & 63, lr = l & 15, lg = l >> 4;
  const int bh = blockIdx.y, b = bh >> 4, h = bh & 15;   // SWAPPED: bh on y
  const int q0 = blockIdx.x * 64;                        // q0 on x (fastest)
  bf16x8 qf[2];
  {
    const short* qbase = qh + ((size_t)(b*SEQ + (q0 + w*16 + lr))*NH + h)*HD;
    qf[0] = *reinterpret_cast<const bf16x8*>(qbase + lg*8);
    qf[1] = *reinterpret_cast<const bf16x8*>(qbase + 32 + lg*8);
  }
  f32x4 oacc[4] = {};
  float lrow[4] = {0.f, 0.f, 0.f, 0.f};
  for (int kt = 0; kt < SEQ/128; ++kt){
    const int kbase = kt * 128;
    __syncthreads();                 // prev PV reads of KP(P)/Vt done
    #pragma unroll
    for (int i = 0; i < 4; ++i){      // K: 128 rows x 8 slots of 8 shorts
      int c = i*256 + t, row = c >> 3, sl = c & 7;
      gld16(kh + (size_t)(b*SEQ + kbase + row)*DM + h*HD + 8*(sl ^ (row & 7)), &KP[c*8]);
    }
    #pragma unroll
    for (int i = 0; i < 4; ++i){      // V: 64 rows x 16 slots
      int c = i*256 + t, row = c >> 4, sl = c & 15;
      gld16(vT + (size_t)(h*HD + row)*NTOK + b*SEQ + kbase + 8*(sl ^ (row & 15)), &Vt[c*8]);
    }
    // R (fp8) directly into accumulator layout (overlaps staging latency)
    f32x4 sa[8];
    #pragma unroll
    for (int tt = 0; tt < 8; ++tt)
      #pragma unroll
      for (int e = 0; e < 4; ++e){
        int row = q0 + w*16 + lg*4 + e;
        sa[tt][e] = fp82f(Rs[((size_t)row*64 + bh)*SEQ + kbase + tt*16 + lr]);
      }
    __syncthreads();                 // staging landed
    #pragma unroll
    for (int s = 0; s < 2; ++s)
      #pragma unroll
      for (int tt = 0; tt < 8; ++tt){
        int krow = tt*16 + lr;
        bf16x8 kf = *reinterpret_cast<const bf16x8*>(&KP[krow*64 + 8*((s*4 + lg) ^ (krow & 7))]);
        sa[tt] = __builtin_amdgcn_mfma_f32_16x16x32_bf16(qf[s], kf, sa[tt], 0, 0, 0);
      }
    __syncthreads();                 // all waves done reading K -> P may overwrite
    float rs_[4] = {0.f, 0.f, 0.f, 0.f};
    #pragma unroll
    for (int tt = 0; tt < 8; ++tt)
      #pragma unroll
      for (int e = 0; e < 4; ++e){
        float p = __expf(sa[tt][e]);
        rs_[e] += p;
        int row = w*16 + lg*4 + e;
        KP[(row*128 + tt*16 + lr) ^ ((row & 7)*8)] = f2bf(p);
      }
    #pragma unroll
    for (int e = 0; e < 4; ++e){
      #pragma unroll
      for (int mm = 1; mm < 16; mm <<= 1)
        rs_[e] += __shfl_xor(rs_[e], mm, 16);
      lrow[e] += rs_[e];
    }
    #pragma unroll
    for (int ks = 0; ks < 4; ++ks){
      int prow = w*16 + lr;
      bf16x8 pa = *reinterpret_cast<const bf16x8*>(&KP[(prow*128 + ks*32 + lg*8) ^ ((prow & 7)*8)]);
      #pragma unroll
      for (int tt = 0; tt < 4; ++tt){
        int vrow = tt*16 + lr;
        bf16x8 vf = *reinterpret_cast<const bf16x8*>(&Vt[vrow*128 + 8*((ks*4 + lg) ^ (vrow & 15))]);
        oacc[tt] = __builtin_amdgcn_mfma_f32_16x16x32_bf16(pa, vf, oacc[tt], 0, 0, 0);
      }
    }
  }
  #pragma unroll
  for (int tt = 0; tt < 4; ++tt){
    #pragma unroll
    for (int e = 0; e < 4; ++e){
      int q = q0 + w*16 + lg*4 + e;
      int hd = tt*16 + lr;
      ao[((size_t)(b*SEQ + q))*DM + h*HD + hd] = f2bf(oacc[tt][e] / lrow[e]);
    }
  }
}

extern "C" void kernel_launch(void* const* d_in, const int* in_sizes, int n_in,
                              void* d_out, int out_size, void* d_ws, size_t ws_size,
                              hipStream_t stream)
{
  const float* q   = (const float*)d_in[0];
  const float* k   = (const float*)d_in[1];
  const float* v   = (const float*)d_in[2];
  const float* rel = (const float*)d_in[3];
  const float* Wq  = (const float*)d_in[4];
  const float* bq  = (const float*)d_in[5];
  const float* Wk  = (const float*)d_in[6];
  const float* bk  = (const float*)d_in[7];
  const float* Wv  = (const float*)d_in[8];
  const float* bv  = (const float*)d_in[9];
  const float* Wo  = (const float*)d_in[10];
  const float* bo  = (const float*)d_in[11];
  float* out = (float*)d_out;

  char* ws = (char*)d_ws;
  short* qb  = (short*)(ws);
  short* kb  = (short*)(ws + 8388608);
  short* vb  = (short*)(ws + 16777216);
  short* qhb = (short*)(ws + 25165824);
  short* khb = (short*)(ws + 33554432);
  short* vTb = (short*)(ws + 41943040);   // [dm=1024][tok=4096]
  short* aob = (short*)(ws + 50331648);
  short* wqb = (short*)(ws + 58720256);
  short* wkb = (short*)(ws + 60817408);
  short* wvb = (short*)(ws + 62914560);
  short* wob = (short*)(ws + 65011712);
  unsigned char* Rs = (unsigned char*)(ws + 67108864);  // [q][bh][k] fp8 = 67MB

  dim3 blk(256);
  {
    int big4 = NTOK*DM/4, small4 = DM*DM/4;
    cvt_all<<<dim3(big4/256, 7), blk, 0, stream>>>(q, k, v, Wq, Wk, Wv, Wo,
        qb, kb, vb, wqb, wkb, wvb, wob, big4, small4);
  }
  proj_gemm<<<dim3(NTOK/128, 24), blk, 0, stream>>>(qb, kb, vb, wqb, wkb, wvb,
      bq, bk, bv, qhb, khb, vTb);
  relscore2<<<dim3(SEQ), blk, 0, stream>>>(qhb, rel, Rs);
  flash4<<<dim3(SEQ/64, NB*NH), blk, 0, stream>>>(qhb, khb, vTb, Rs, aob);
  out_gemm<<<dim3(NTOK/128, DM/128), blk, 0, stream>>>(aob, wob, bo, out);
}

// Round 12
// 232.834 us; speedup vs baseline: 1.0233x; 1.0233x over previous
//
#include <hip/hip_runtime.h>
#include <hip/hip_bf16.h>

#define NB 4
#define SEQ 1024
#define DM 1024
#define NH 16
#define HD 64
#define QSCALE 0.125f
#define NTOK (NB*SEQ)

using f32x4  = __attribute__((ext_vector_type(4))) float;
using bf16x8 = __attribute__((ext_vector_type(8))) short;
using s16x4  = __attribute__((ext_vector_type(4))) short;

__device__ __forceinline__ short f2bf(float x){
  __hip_bfloat16 h = __float2bfloat16(x);
  return *reinterpret_cast<short*>(&h);
}
__device__ __forceinline__ float bf2f(short x){
  __hip_bfloat16 h; *reinterpret_cast<short*>(&h) = x;
  return __bfloat162float(h);
}
// fp8 e4m3 (OCP on gfx950) encode/decode via the HW cvt pair — roundtrip-consistent.
__device__ __forceinline__ unsigned char f2fp8(float x){
  int d = __builtin_amdgcn_cvt_pk_fp8_f32(x, x, 0, false);
  return (unsigned char)(d & 0xff);
}
__device__ __forceinline__ float fp82f(unsigned char x){
  return __builtin_amdgcn_cvt_f32_fp8((int)x, 0);
}

// async global->LDS, 16B per lane; LDS dest = wave-uniform base + lane*16.
__device__ __forceinline__ void gld16(const void* g, void* l){
  __builtin_amdgcn_global_load_lds(
      (const __attribute__((address_space(1))) unsigned int*)g,
      (__attribute__((address_space(3))) unsigned int*)l, 16, 0, 0);
}

// ---------------- fp32 -> bf16 convert, all 7 tensors in one dispatch ----------
__global__ void cvt_all(const float* __restrict__ a0, const float* __restrict__ a1,
                        const float* __restrict__ a2, const float* __restrict__ a3,
                        const float* __restrict__ a4, const float* __restrict__ a5,
                        const float* __restrict__ a6,
                        short* o0, short* o1, short* o2, short* o3,
                        short* o4, short* o5, short* o6, int big4, int small4){
  int i = blockIdx.x * blockDim.x + threadIdx.x;
  int y = blockIdx.y;
  int n4 = (y < 3) ? big4 : small4;
  if (i >= n4) return;
  const float* in; short* out;
  if      (y == 0){ in = a0; out = o0; }
  else if (y == 1){ in = a1; out = o1; }
  else if (y == 2){ in = a2; out = o2; }
  else if (y == 3){ in = a3; out = o3; }
  else if (y == 4){ in = a4; out = o4; }
  else if (y == 5){ in = a5; out = o5; }
  else            { in = a6; out = o6; }
  float4 v = reinterpret_cast<const float4*>(in)[i];
  s16x4 o;
  o[0] = f2bf(v.x); o[1] = f2bf(v.y); o[2] = f2bf(v.z); o[3] = f2bf(v.w);
  reinterpret_cast<s16x4*>(out)[i] = o;
}

// ------------- fused Q/K/V projection GEMMs, m97 structure (R6-proven) ----------
__global__ __launch_bounds__(256) void proj_gemm(
    const short* __restrict__ qb, const short* __restrict__ kb, const short* __restrict__ vb,
    const short* __restrict__ wqb, const short* __restrict__ wkb, const short* __restrict__ wvb,
    const float* __restrict__ bq, const float* __restrict__ bk, const float* __restrict__ bv,
    short* __restrict__ qhb, short* __restrict__ khb, short* __restrict__ vTb)
{
  __shared__ short As[128*32];
  __shared__ short Bs[128*32];
  const int t = threadIdx.x, w = t >> 6, l = t & 63, lr = l & 15, lg = l >> 4;
  const int wr = w >> 1, wc = w & 1;
  const int which = blockIdx.y >> 3;
  const short *A, *Bt;
  int m0, n0;
  if (which == 2){ A = wvb; Bt = vb; m0 = (blockIdx.y & 7)*128; n0 = blockIdx.x*128; }
  else if (which == 1){ A = kb; Bt = wkb; m0 = blockIdx.x*128; n0 = (blockIdx.y & 7)*128; }
  else { A = qb; Bt = wqb; m0 = blockIdx.x*128; n0 = (blockIdx.y & 7)*128; }
  f32x4 acc[4][4] = {};
  for (int k0 = 0; k0 < DM; k0 += 32){
    __syncthreads();
    #pragma unroll
    for (int i = 0; i < 2; ++i){
      int c = i*256 + t, row = c >> 2, sl = c & 3;
      gld16(A  + (size_t)(m0 + row)*DM + k0 + sl*8, &As[c*8]);
      gld16(Bt + (size_t)(n0 + row)*DM + k0 + sl*8, &Bs[c*8]);
    }
    __syncthreads();
    bf16x8 af[4], bfr[4];
    #pragma unroll
    for (int m = 0; m < 4; ++m)
      af[m] = *reinterpret_cast<const bf16x8*>(&As[(wr*64 + m*16 + lr)*32 + lg*8]);
    #pragma unroll
    for (int n = 0; n < 4; ++n)
      bfr[n] = *reinterpret_cast<const bf16x8*>(&Bs[(wc*64 + n*16 + lr)*32 + lg*8]);
    #pragma unroll
    for (int m = 0; m < 4; ++m)
      #pragma unroll
      for (int n = 0; n < 4; ++n)
        acc[m][n] = __builtin_amdgcn_mfma_f32_16x16x32_bf16(af[m], bfr[n], acc[m][n], 0, 0, 0);
  }
  #pragma unroll
  for (int m = 0; m < 4; ++m){
    int row = m0 + wr*64 + m*16 + lg*4;
    #pragma unroll
    for (int n = 0; n < 4; ++n){
      int col = n0 + wc*64 + n*16 + lr;
      #pragma unroll
      for (int e = 0; e < 4; ++e){
        if (which == 0)
          qhb[(size_t)(row + e)*DM + col] = f2bf((acc[m][n][e] + bq[col]) * QSCALE);
        else if (which == 1)
          khb[(size_t)(row + e)*DM + col] = f2bf(acc[m][n][e] + bk[col]);
        else
          vTb[(size_t)(row + e)*NTOK + col] = f2bf(acc[m][n][e] + bv[row + e]);
      }
    }
  }
}

// ------------- out GEMM: out = aob @ Wo^T + bo (R6-proven) ----------------------
__global__ __launch_bounds__(256) void out_gemm(const short* __restrict__ A,
    const short* __restrict__ Bt, const float* __restrict__ bias, float* __restrict__ out)
{
  __shared__ short As[128*32];
  __shared__ short Bs[128*32];
  const int t = threadIdx.x, w = t >> 6, l = t & 63, lr = l & 15, lg = l >> 4;
  const int wr = w >> 1, wc = w & 1;
  const int m0 = blockIdx.x*128, n0 = blockIdx.y*128;
  f32x4 acc[4][4] = {};
  for (int k0 = 0; k0 < DM; k0 += 32){
    __syncthreads();
    #pragma unroll
    for (int i = 0; i < 2; ++i){
      int c = i*256 + t, row = c >> 2, sl = c & 3;
      gld16(A  + (size_t)(m0 + row)*DM + k0 + sl*8, &As[c*8]);
      gld16(Bt + (size_t)(n0 + row)*DM + k0 + sl*8, &Bs[c*8]);
    }
    __syncthreads();
    bf16x8 af[4], bfr[4];
    #pragma unroll
    for (int m = 0; m < 4; ++m)
      af[m] = *reinterpret_cast<const bf16x8*>(&As[(wr*64 + m*16 + lr)*32 + lg*8]);
    #pragma unroll
    for (int n = 0; n < 4; ++n)
      bfr[n] = *reinterpret_cast<const bf16x8*>(&Bs[(wc*64 + n*16 + lr)*32 + lg*8]);
    #pragma unroll
    for (int m = 0; m < 4; ++m)
      #pragma unroll
      for (int n = 0; n < 4; ++n)
        acc[m][n] = __builtin_amdgcn_mfma_f32_16x16x32_bf16(af[m], bfr[n], acc[m][n], 0, 0, 0);
  }
  #pragma unroll
  for (int m = 0; m < 4; ++m){
    int row = m0 + wr*64 + m*16 + lg*4;
    #pragma unroll
    for (int n = 0; n < 4; ++n){
      int col = n0 + wc*64 + n*16 + lr;
      float bb = bias[col];
      #pragma unroll
      for (int e = 0; e < 4; ++e)
        out[(size_t)(row + e)*DM + col] = acc[m][n][e] + bb;
    }
  }
}

// ------------- rel scores (R6-proven): Rs[q][bh][k] fp8 -------------------------
__global__ __launch_bounds__(256) void relscore2(const short* __restrict__ qh,
    const float* __restrict__ rel, unsigned char* __restrict__ Rs)
{
  __shared__ short At[64*72];   // [bh][d]
  __shared__ short Bs[64*72];   // [k][d] bf16
  const int t = threadIdx.x, w = t >> 6, l = t & 63, lr = l & 15, lg = l >> 4;
  const int q = blockIdx.x;
  #pragma unroll
  for (int i = 0; i < 2; ++i){
    int c = t + i*256;
    int row = c >> 3, off = (c & 7) * 8;
    int b = row >> 4, h = row & 15;
    uint4 v = *reinterpret_cast<const uint4*>(qh + ((size_t)(b*SEQ + q)*NH + h)*HD + off);
    *reinterpret_cast<uint4*>(&At[row*72 + off]) = v;
  }
  __syncthreads();
  bf16x8 af[2];
  af[0] = *reinterpret_cast<const bf16x8*>(&At[(w*16 + lr)*72 + lg*8]);
  af[1] = *reinterpret_cast<const bf16x8*>(&At[(w*16 + lr)*72 + 32 + lg*8]);
  for (int k0 = 0; k0 < SEQ; k0 += 64){
    __syncthreads();
    #pragma unroll
    for (int i = 0; i < 4; ++i){
      int c = t + i*256;
      int row = c >> 4, off = (c & 15) * 4;
      float4 v = *reinterpret_cast<const float4*>(rel + ((size_t)q*SEQ + k0 + row)*HD + off);
      s16x4 o;
      o[0] = f2bf(v.x); o[1] = f2bf(v.y); o[2] = f2bf(v.z); o[3] = f2bf(v.w);
      *reinterpret_cast<s16x4*>(&Bs[row*72 + off]) = o;
    }
    __syncthreads();
    f32x4 acc[4] = {};
    #pragma unroll
    for (int s = 0; s < 2; ++s){
      #pragma unroll
      for (int tt = 0; tt < 4; ++tt){
        bf16x8 bf = *reinterpret_cast<const bf16x8*>(&Bs[(tt*16 + lr)*72 + s*32 + lg*8]);
        acc[tt] = __builtin_amdgcn_mfma_f32_16x16x32_bf16(af[s], bf, acc[tt], 0, 0, 0);
      }
    }
    #pragma unroll
    for (int tt = 0; tt < 4; ++tt){
      #pragma unroll
      for (int e = 0; e < 4; ++e){
        int bh = w*16 + lg*4 + e;
        Rs[((size_t)q*64 + bh)*SEQ + k0 + tt*16 + lr] = f2fp8(acc[tt][e]);
      }
    }
  }
}

// ------------- flash4 (R10-proven): P aliased onto K's LDS, grid (bh, q0) -------
__global__ __launch_bounds__(256, 4) void flash4(const short* __restrict__ qh,
    const short* __restrict__ kh, const short* __restrict__ vT,
    const unsigned char* __restrict__ Rs, short* __restrict__ ao)
{
  __shared__ short KP[128*64];   // phase A: K [k][d] chunk^(row&7); phase B: P [q][k] swizzled
  __shared__ short Vt[64*128];   // [hd][k] chunk^(row&15) swizzle
  const int t = threadIdx.x, w = t >> 6, l = t & 63, lr = l & 15, lg = l >> 4;
  const int bh = blockIdx.x, b = bh >> 4, h = bh & 15;
  const int q0 = blockIdx.y * 64;
  bf16x8 qf[2];
  {
    const short* qbase = qh + ((size_t)(b*SEQ + (q0 + w*16 + lr))*NH + h)*HD;
    qf[0] = *reinterpret_cast<const bf16x8*>(qbase + lg*8);
    qf[1] = *reinterpret_cast<const bf16x8*>(qbase + 32 + lg*8);
  }
  f32x4 oacc[4] = {};
  float lrow[4] = {0.f, 0.f, 0.f, 0.f};
  for (int kt = 0; kt < SEQ/128; ++kt){
    const int kbase = kt * 128;
    __syncthreads();                 // prev PV reads of KP(P)/Vt done
    #pragma unroll
    for (int i = 0; i < 4; ++i){      // K: 128 rows x 8 slots of 8 shorts
      int c = i*256 + t, row = c >> 3, sl = c & 7;
      gld16(kh + (size_t)(b*SEQ + kbase + row)*DM + h*HD + 8*(sl ^ (row & 7)), &KP[c*8]);
    }
    #pragma unroll
    for (int i = 0; i < 4; ++i){      // V: 64 rows x 16 slots
      int c = i*256 + t, row = c >> 4, sl = c & 15;
      gld16(vT + (size_t)(h*HD + row)*NTOK + b*SEQ + kbase + 8*(sl ^ (row & 15)), &Vt[c*8]);
    }
    // R (fp8) directly into accumulator layout (overlaps staging latency)
    f32x4 sa[8];
    #pragma unroll
    for (int tt = 0; tt < 8; ++tt)
      #pragma unroll
      for (int e = 0; e < 4; ++e){
        int row = q0 + w*16 + lg*4 + e;
        sa[tt][e] = fp82f(Rs[((size_t)row*64 + bh)*SEQ + kbase + tt*16 + lr]);
      }
    __syncthreads();                 // staging landed
    #pragma unroll
    for (int s = 0; s < 2; ++s)
      #pragma unroll
      for (int tt = 0; tt < 8; ++tt){
        int krow = tt*16 + lr;
        bf16x8 kf = *reinterpret_cast<const bf16x8*>(&KP[krow*64 + 8*((s*4 + lg) ^ (krow & 7))]);
        sa[tt] = __builtin_amdgcn_mfma_f32_16x16x32_bf16(qf[s], kf, sa[tt], 0, 0, 0);
      }
    __syncthreads();                 // all waves done reading K -> P may overwrite
    float rs_[4] = {0.f, 0.f, 0.f, 0.f};
    #pragma unroll
    for (int tt = 0; tt < 8; ++tt)
      #pragma unroll
      for (int e = 0; e < 4; ++e){
        float p = __expf(sa[tt][e]);
        rs_[e] += p;
        int row = w*16 + lg*4 + e;
        KP[(row*128 + tt*16 + lr) ^ ((row & 7)*8)] = f2bf(p);
      }
    #pragma unroll
    for (int e = 0; e < 4; ++e){
      #pragma unroll
      for (int mm = 1; mm < 16; mm <<= 1)
        rs_[e] += __shfl_xor(rs_[e], mm, 16);
      lrow[e] += rs_[e];
    }
    #pragma unroll
    for (int ks = 0; ks < 4; ++ks){
      int prow = w*16 + lr;
      bf16x8 pa = *reinterpret_cast<const bf16x8*>(&KP[(prow*128 + ks*32 + lg*8) ^ ((prow & 7)*8)]);
      #pragma unroll
      for (int tt = 0; tt < 4; ++tt){
        int vrow = tt*16 + lr;
        bf16x8 vf = *reinterpret_cast<const bf16x8*>(&Vt[vrow*128 + 8*((ks*4 + lg) ^ (vrow & 15))]);
        oacc[tt] = __builtin_amdgcn_mfma_f32_16x16x32_bf16(pa, vf, oacc[tt], 0, 0, 0);
      }
    }
  }
  #pragma unroll
  for (int tt = 0; tt < 4; ++tt){
    #pragma unroll
    for (int e = 0; e < 4; ++e){
      int q = q0 + w*16 + lg*4 + e;
      int hd = tt*16 + lr;
      ao[((size_t)(b*SEQ + q))*DM + h*HD + hd] = f2bf(oacc[tt][e] / lrow[e]);
    }
  }
}

extern "C" void kernel_launch(void* const* d_in, const int* in_sizes, int n_in,
                              void* d_out, int out_size, void* d_ws, size_t ws_size,
                              hipStream_t stream)
{
  const float* q   = (const float*)d_in[0];
  const float* k   = (const float*)d_in[1];
  const float* v   = (const float*)d_in[2];
  const float* rel = (const float*)d_in[3];
  const float* Wq  = (const float*)d_in[4];
  const float* bq  = (const float*)d_in[5];
  const float* Wk  = (const float*)d_in[6];
  const float* bk  = (const float*)d_in[7];
  const float* Wv  = (const float*)d_in[8];
  const float* bv  = (const float*)d_in[9];
  const float* Wo  = (const float*)d_in[10];
  const float* bo  = (const float*)d_in[11];
  float* out = (float*)d_out;

  char* ws = (char*)d_ws;
  short* qb  = (short*)(ws);
  short* kb  = (short*)(ws + 8388608);
  short* vb  = (short*)(ws + 16777216);
  short* qhb = (short*)(ws + 25165824);
  short* khb = (short*)(ws + 33554432);
  short* vTb = (short*)(ws + 41943040);   // [dm=1024][tok=4096]
  short* aob = (short*)(ws + 50331648);
  short* wqb = (short*)(ws + 58720256);
  short* wkb = (short*)(ws + 60817408);
  short* wvb = (short*)(ws + 62914560);
  short* wob = (short*)(ws + 65011712);
  unsigned char* Rs = (unsigned char*)(ws + 67108864);  // [q][bh][k] fp8 = 67MB

  dim3 blk(256);
  {
    int big4 = NTOK*DM/4, small4 = DM*DM/4;
    cvt_all<<<dim3(big4/256, 7), blk, 0, stream>>>(q, k, v, Wq, Wk, Wv, Wo,
        qb, kb, vb, wqb, wkb, wvb, wob, big4, small4);
  }
  proj_gemm<<<dim3(NTOK/128, 24), blk, 0, stream>>>(qb, kb, vb, wqb, wkb, wvb,
      bq, bk, bv, qhb, khb, vTb);
  relscore2<<<dim3(SEQ), blk, 0, stream>>>(qhb, rel, Rs);
  flash4<<<dim3(NB*NH, SEQ/64), blk, 0, stream>>>(qhb, khb, vTb, Rs, aob);
  out_gemm<<<dim3(NTOK/128, DM/128), blk, 0, stream>>>(aob, wob, bo, out);
}

// Round 13
// 229.602 us; speedup vs baseline: 1.0377x; 1.0141x over previous
//
#include <hip/hip_runtime.h>
#include <hip/hip_bf16.h>

#define NB 4
#define SEQ 1024
#define DM 1024
#define NH 16
#define HD 64
#define QSCALE 0.125f
#define NTOK (NB*SEQ)

using f32x4  = __attribute__((ext_vector_type(4))) float;
using bf16x8 = __attribute__((ext_vector_type(8))) short;
using s16x4  = __attribute__((ext_vector_type(4))) short;

__device__ __forceinline__ short f2bf(float x){
  __hip_bfloat16 h = __float2bfloat16(x);
  return *reinterpret_cast<short*>(&h);
}
__device__ __forceinline__ float bf2f(short x){
  __hip_bfloat16 h; *reinterpret_cast<short*>(&h) = x;
  return __bfloat162float(h);
}
// fp8 e4m3 (OCP on gfx950) encode/decode via the HW cvt pair — roundtrip-consistent.
__device__ __forceinline__ unsigned char f2fp8(float x){
  int d = __builtin_amdgcn_cvt_pk_fp8_f32(x, x, 0, false);
  return (unsigned char)(d & 0xff);
}
__device__ __forceinline__ float fp82f(unsigned char x){
  return __builtin_amdgcn_cvt_f32_fp8((int)x, 0);
}

// async global->LDS, 16B per lane; LDS dest = wave-uniform base + lane*16.
__device__ __forceinline__ void gld16(const void* g, void* l){
  __builtin_amdgcn_global_load_lds(
      (const __attribute__((address_space(1))) unsigned int*)g,
      (__attribute__((address_space(3))) unsigned int*)l, 16, 0, 0);
}

// ---------------- fp32 -> bf16 convert, all 7 tensors in one dispatch ----------
__global__ void cvt_all(const float* __restrict__ a0, const float* __restrict__ a1,
                        const float* __restrict__ a2, const float* __restrict__ a3,
                        const float* __restrict__ a4, const float* __restrict__ a5,
                        const float* __restrict__ a6,
                        short* o0, short* o1, short* o2, short* o3,
                        short* o4, short* o5, short* o6, int big4, int small4){
  int i = blockIdx.x * blockDim.x + threadIdx.x;
  int y = blockIdx.y;
  int n4 = (y < 3) ? big4 : small4;
  if (i >= n4) return;
  const float* in; short* out;
  if      (y == 0){ in = a0; out = o0; }
  else if (y == 1){ in = a1; out = o1; }
  else if (y == 2){ in = a2; out = o2; }
  else if (y == 3){ in = a3; out = o3; }
  else if (y == 4){ in = a4; out = o4; }
  else if (y == 5){ in = a5; out = o5; }
  else            { in = a6; out = o6; }
  float4 v = reinterpret_cast<const float4*>(in)[i];
  s16x4 o;
  o[0] = f2bf(v.x); o[1] = f2bf(v.y); o[2] = f2bf(v.z); o[3] = f2bf(v.w);
  reinterpret_cast<s16x4*>(out)[i] = o;
}

// ------------- fused Q/K/V projection GEMMs, m97 structure (R6-proven) ----------
__global__ __launch_bounds__(256) void proj_gemm(
    const short* __restrict__ qb, const short* __restrict__ kb, const short* __restrict__ vb,
    const short* __restrict__ wqb, const short* __restrict__ wkb, const short* __restrict__ wvb,
    const float* __restrict__ bq, const float* __restrict__ bk, const float* __restrict__ bv,
    short* __restrict__ qhb, short* __restrict__ khb, short* __restrict__ vTb)
{
  __shared__ short As[128*32];
  __shared__ short Bs[128*32];
  const int t = threadIdx.x, w = t >> 6, l = t & 63, lr = l & 15, lg = l >> 4;
  const int wr = w >> 1, wc = w & 1;
  const int which = blockIdx.y >> 3;
  const short *A, *Bt;
  int m0, n0;
  if (which == 2){ A = wvb; Bt = vb; m0 = (blockIdx.y & 7)*128; n0 = blockIdx.x*128; }
  else if (which == 1){ A = kb; Bt = wkb; m0 = blockIdx.x*128; n0 = (blockIdx.y & 7)*128; }
  else { A = qb; Bt = wqb; m0 = blockIdx.x*128; n0 = (blockIdx.y & 7)*128; }
  f32x4 acc[4][4] = {};
  for (int k0 = 0; k0 < DM; k0 += 32){
    __syncthreads();
    #pragma unroll
    for (int i = 0; i < 2; ++i){
      int c = i*256 + t, row = c >> 2, sl = c & 3;
      gld16(A  + (size_t)(m0 + row)*DM + k0 + sl*8, &As[c*8]);
      gld16(Bt + (size_t)(n0 + row)*DM + k0 + sl*8, &Bs[c*8]);
    }
    __syncthreads();
    bf16x8 af[4], bfr[4];
    #pragma unroll
    for (int m = 0; m < 4; ++m)
      af[m] = *reinterpret_cast<const bf16x8*>(&As[(wr*64 + m*16 + lr)*32 + lg*8]);
    #pragma unroll
    for (int n = 0; n < 4; ++n)
      bfr[n] = *reinterpret_cast<const bf16x8*>(&Bs[(wc*64 + n*16 + lr)*32 + lg*8]);
    #pragma unroll
    for (int m = 0; m < 4; ++m)
      #pragma unroll
      for (int n = 0; n < 4; ++n)
        acc[m][n] = __builtin_amdgcn_mfma_f32_16x16x32_bf16(af[m], bfr[n], acc[m][n], 0, 0, 0);
  }
  #pragma unroll
  for (int m = 0; m < 4; ++m){
    int row = m0 + wr*64 + m*16 + lg*4;
    #pragma unroll
    for (int n = 0; n < 4; ++n){
      int col = n0 + wc*64 + n*16 + lr;
      #pragma unroll
      for (int e = 0; e < 4; ++e){
        if (which == 0)
          qhb[(size_t)(row + e)*DM + col] = f2bf((acc[m][n][e] + bq[col]) * QSCALE);
        else if (which == 1)
          khb[(size_t)(row + e)*DM + col] = f2bf(acc[m][n][e] + bk[col]);
        else
          vTb[(size_t)(row + e)*NTOK + col] = f2bf(acc[m][n][e] + bv[row + e]);
      }
    }
  }
}

// ------------- out GEMM v2: 128x64 tile, grid (32,16) = 2 blocks/CU -------------
// 1 block/CU exposed every barrier drain (no co-resident block to fill the stall,
// m114); halving the tile doubles co-residency. Same K-loop order -> bit-identical.
__global__ __launch_bounds__(256) void out_gemm(const short* __restrict__ A,
    const short* __restrict__ Bt, const float* __restrict__ bias, float* __restrict__ out)
{
  __shared__ short As[128*32];
  __shared__ short Bs[64*32];
  const int t = threadIdx.x, w = t >> 6, l = t & 63, lr = l & 15, lg = l >> 4;
  const int m0 = blockIdx.x*128, n0 = blockIdx.y*64;
  f32x4 acc[2][4] = {};
  for (int k0 = 0; k0 < DM; k0 += 32){
    __syncthreads();
    #pragma unroll
    for (int i = 0; i < 2; ++i){
      int c = i*256 + t, row = c >> 2, sl = c & 3;
      gld16(A + (size_t)(m0 + row)*DM + k0 + sl*8, &As[c*8]);
    }
    {
      int row = t >> 2, sl = t & 3;   // 64 rows x 4 chunks = 256 lanes, 1 iter
      gld16(Bt + (size_t)(n0 + row)*DM + k0 + sl*8, &Bs[t*8]);
    }
    __syncthreads();
    bf16x8 af[2], bfr[4];
    #pragma unroll
    for (int m = 0; m < 2; ++m)
      af[m] = *reinterpret_cast<const bf16x8*>(&As[(w*32 + m*16 + lr)*32 + lg*8]);
    #pragma unroll
    for (int n = 0; n < 4; ++n)
      bfr[n] = *reinterpret_cast<const bf16x8*>(&Bs[(n*16 + lr)*32 + lg*8]);
    #pragma unroll
    for (int m = 0; m < 2; ++m)
      #pragma unroll
      for (int n = 0; n < 4; ++n)
        acc[m][n] = __builtin_amdgcn_mfma_f32_16x16x32_bf16(af[m], bfr[n], acc[m][n], 0, 0, 0);
  }
  #pragma unroll
  for (int m = 0; m < 2; ++m){
    int row = m0 + w*32 + m*16 + lg*4;
    #pragma unroll
    for (int n = 0; n < 4; ++n){
      int col = n0 + n*16 + lr;
      float bb = bias[col];
      #pragma unroll
      for (int e = 0; e < 4; ++e)
        out[(size_t)(row + e)*DM + col] = acc[m][n][e] + bb;
    }
  }
}

// ------------- rel scores (R6-proven): Rs[q][bh][k] fp8 -------------------------
__global__ __launch_bounds__(256) void relscore2(const short* __restrict__ qh,
    const float* __restrict__ rel, unsigned char* __restrict__ Rs)
{
  __shared__ short At[64*72];   // [bh][d]
  __shared__ short Bs[64*72];   // [k][d] bf16
  const int t = threadIdx.x, w = t >> 6, l = t & 63, lr = l & 15, lg = l >> 4;
  const int q = blockIdx.x;
  #pragma unroll
  for (int i = 0; i < 2; ++i){
    int c = t + i*256;
    int row = c >> 3, off = (c & 7) * 8;
    int b = row >> 4, h = row & 15;
    uint4 v = *reinterpret_cast<const uint4*>(qh + ((size_t)(b*SEQ + q)*NH + h)*HD + off);
    *reinterpret_cast<uint4*>(&At[row*72 + off]) = v;
  }
  __syncthreads();
  bf16x8 af[2];
  af[0] = *reinterpret_cast<const bf16x8*>(&At[(w*16 + lr)*72 + lg*8]);
  af[1] = *reinterpret_cast<const bf16x8*>(&At[(w*16 + lr)*72 + 32 + lg*8]);
  for (int k0 = 0; k0 < SEQ; k0 += 64){
    __syncthreads();
    #pragma unroll
    for (int i = 0; i < 4; ++i){
      int c = t + i*256;
      int row = c >> 4, off = (c & 15) * 4;
      float4 v = *reinterpret_cast<const float4*>(rel + ((size_t)q*SEQ + k0 + row)*HD + off);
      s16x4 o;
      o[0] = f2bf(v.x); o[1] = f2bf(v.y); o[2] = f2bf(v.z); o[3] = f2bf(v.w);
      *reinterpret_cast<s16x4*>(&Bs[row*72 + off]) = o;
    }
    __syncthreads();
    f32x4 acc[4] = {};
    #pragma unroll
    for (int s = 0; s < 2; ++s){
      #pragma unroll
      for (int tt = 0; tt < 4; ++tt){
        bf16x8 bf = *reinterpret_cast<const bf16x8*>(&Bs[(tt*16 + lr)*72 + s*32 + lg*8]);
        acc[tt] = __builtin_amdgcn_mfma_f32_16x16x32_bf16(af[s], bf, acc[tt], 0, 0, 0);
      }
    }
    #pragma unroll
    for (int tt = 0; tt < 4; ++tt){
      #pragma unroll
      for (int e = 0; e < 4; ++e){
        int bh = w*16 + lg*4 + e;
        Rs[((size_t)q*64 + bh)*SEQ + k0 + tt*16 + lr] = f2fp8(acc[tt][e]);
      }
    }
  }
}

// ------------- flash4 (R10-proven): P aliased onto K's LDS, grid (bh, q0) -------
__global__ __launch_bounds__(256, 4) void flash4(const short* __restrict__ qh,
    const short* __restrict__ kh, const short* __restrict__ vT,
    const unsigned char* __restrict__ Rs, short* __restrict__ ao)
{
  __shared__ short KP[128*64];   // phase A: K [k][d] chunk^(row&7); phase B: P [q][k] swizzled
  __shared__ short Vt[64*128];   // [hd][k] chunk^(row&15) swizzle
  const int t = threadIdx.x, w = t >> 6, l = t & 63, lr = l & 15, lg = l >> 4;
  const int bh = blockIdx.x, b = bh >> 4, h = bh & 15;
  const int q0 = blockIdx.y * 64;
  bf16x8 qf[2];
  {
    const short* qbase = qh + ((size_t)(b*SEQ + (q0 + w*16 + lr))*NH + h)*HD;
    qf[0] = *reinterpret_cast<const bf16x8*>(qbase + lg*8);
    qf[1] = *reinterpret_cast<const bf16x8*>(qbase + 32 + lg*8);
  }
  f32x4 oacc[4] = {};
  float lrow[4] = {0.f, 0.f, 0.f, 0.f};
  for (int kt = 0; kt < SEQ/128; ++kt){
    const int kbase = kt * 128;
    __syncthreads();                 // prev PV reads of KP(P)/Vt done
    #pragma unroll
    for (int i = 0; i < 4; ++i){      // K: 128 rows x 8 slots of 8 shorts
      int c = i*256 + t, row = c >> 3, sl = c & 7;
      gld16(kh + (size_t)(b*SEQ + kbase + row)*DM + h*HD + 8*(sl ^ (row & 7)), &KP[c*8]);
    }
    #pragma unroll
    for (int i = 0; i < 4; ++i){      // V: 64 rows x 16 slots
      int c = i*256 + t, row = c >> 4, sl = c & 15;
      gld16(vT + (size_t)(h*HD + row)*NTOK + b*SEQ + kbase + 8*(sl ^ (row & 15)), &Vt[c*8]);
    }
    // R (fp8) directly into accumulator layout (overlaps staging latency)
    f32x4 sa[8];
    #pragma unroll
    for (int tt = 0; tt < 8; ++tt)
      #pragma unroll
      for (int e = 0; e < 4; ++e){
        int row = q0 + w*16 + lg*4 + e;
        sa[tt][e] = fp82f(Rs[((size_t)row*64 + bh)*SEQ + kbase + tt*16 + lr]);
      }
    __syncthreads();                 // staging landed
    #pragma unroll
    for (int s = 0; s < 2; ++s)
      #pragma unroll
      for (int tt = 0; tt < 8; ++tt){
        int krow = tt*16 + lr;
        bf16x8 kf = *reinterpret_cast<const bf16x8*>(&KP[krow*64 + 8*((s*4 + lg) ^ (krow & 7))]);
        sa[tt] = __builtin_amdgcn_mfma_f32_16x16x32_bf16(qf[s], kf, sa[tt], 0, 0, 0);
      }
    __syncthreads();                 // all waves done reading K -> P may overwrite
    float rs_[4] = {0.f, 0.f, 0.f, 0.f};
    #pragma unroll
    for (int tt = 0; tt < 8; ++tt)
      #pragma unroll
      for (int e = 0; e < 4; ++e){
        float p = __expf(sa[tt][e]);
        rs_[e] += p;
        int row = w*16 + lg*4 + e;
        KP[(row*128 + tt*16 + lr) ^ ((row & 7)*8)] = f2bf(p);
      }
    #pragma unroll
    for (int e = 0; e < 4; ++e){
      #pragma unroll
      for (int mm = 1; mm < 16; mm <<= 1)
        rs_[e] += __shfl_xor(rs_[e], mm, 16);
      lrow[e] += rs_[e];
    }
    #pragma unroll
    for (int ks = 0; ks < 4; ++ks){
      int prow = w*16 + lr;
      bf16x8 pa = *reinterpret_cast<const bf16x8*>(&KP[(prow*128 + ks*32 + lg*8) ^ ((prow & 7)*8)]);
      #pragma unroll
      for (int tt = 0; tt < 4; ++tt){
        int vrow = tt*16 + lr;
        bf16x8 vf = *reinterpret_cast<const bf16x8*>(&Vt[vrow*128 + 8*((ks*4 + lg) ^ (vrow & 15))]);
        oacc[tt] = __builtin_amdgcn_mfma_f32_16x16x32_bf16(pa, vf, oacc[tt], 0, 0, 0);
      }
    }
  }
  #pragma unroll
  for (int tt = 0; tt < 4; ++tt){
    #pragma unroll
    for (int e = 0; e < 4; ++e){
      int q = q0 + w*16 + lg*4 + e;
      int hd = tt*16 + lr;
      ao[((size_t)(b*SEQ + q))*DM + h*HD + hd] = f2bf(oacc[tt][e] / lrow[e]);
    }
  }
}

extern "C" void kernel_launch(void* const* d_in, const int* in_sizes, int n_in,
                              void* d_out, int out_size, void* d_ws, size_t ws_size,
                              hipStream_t stream)
{
  const float* q   = (const float*)d_in[0];
  const float* k   = (const float*)d_in[1];
  const float* v   = (const float*)d_in[2];
  const float* rel = (const float*)d_in[3];
  const float* Wq  = (const float*)d_in[4];
  const float* bq  = (const float*)d_in[5];
  const float* Wk  = (const float*)d_in[6];
  const float* bk  = (const float*)d_in[7];
  const float* Wv  = (const float*)d_in[8];
  const float* bv  = (const float*)d_in[9];
  const float* Wo  = (const float*)d_in[10];
  const float* bo  = (const float*)d_in[11];
  float* out = (float*)d_out;

  char* ws = (char*)d_ws;
  short* qb  = (short*)(ws);
  short* kb  = (short*)(ws + 8388608);
  short* vb  = (short*)(ws + 16777216);
  short* qhb = (short*)(ws + 25165824);
  short* khb = (short*)(ws + 33554432);
  short* vTb = (short*)(ws + 41943040);   // [dm=1024][tok=4096]
  short* aob = (short*)(ws + 50331648);
  short* wqb = (short*)(ws + 58720256);
  short* wkb = (short*)(ws + 60817408);
  short* wvb = (short*)(ws + 62914560);
  short* wob = (short*)(ws + 65011712);
  unsigned char* Rs = (unsigned char*)(ws + 67108864);  // [q][bh][k] fp8 = 67MB

  dim3 blk(256);
  {
    int big4 = NTOK*DM/4, small4 = DM*DM/4;
    cvt_all<<<dim3(big4/256, 7), blk, 0, stream>>>(q, k, v, Wq, Wk, Wv, Wo,
        qb, kb, vb, wqb, wkb, wvb, wob, big4, small4);
  }
  proj_gemm<<<dim3(NTOK/128, 24), blk, 0, stream>>>(qb, kb, vb, wqb, wkb, wvb,
      bq, bk, bv, qhb, khb, vTb);
  relscore2<<<dim3(SEQ), blk, 0, stream>>>(qhb, rel, Rs);
  flash4<<<dim3(NB*NH, SEQ/64), blk, 0, stream>>>(qhb, khb, vTb, Rs, aob);
  out_gemm<<<dim3(NTOK/128, DM/64), blk, 0, stream>>>(aob, wob, bo, out);
}